// Round 6
// baseline (479.384 us; speedup 1.0000x reference)
//
#include <hip/hip_runtime.h>

#define DIM   256
#define HW_   1024
#define NROWS 32768
#define KEMB  4096

// ---------------- ws layout ----------------
// [0,       131072)  int    idx[32768]
// [131072,  262144)  float  S[32768]
// [262144,  278528)  float  E[4096]
// [278528,  278536)  double loss_sum
// [278536,  278540)  int    done (epilogue finalize counter)
// [278592,  409664)  int    cnt[32768]
// [409664,  540736)  uint   rowmin_enc[32768]
// [540736,  1589312) int    cand[32768][8]
// [1589312, 3686464) short  ebuf2[4096*512]  (bf16, 32x32-frag-major)
#define WS_S_OFF    131072
#define WS_E_OFF    262144
#define WS_LOSS_OFF 278528
#define WS_DONE_OFF 278536
#define WS_CNT_OFF  278592
#define WS_RMIN_OFF 409664
#define WS_CAND_OFF 540736
#define WS_EBUF_OFF 1589312
#define WS_NEEDED   3686464
#define RESCUE_W    1.5e-4f

typedef __attribute__((ext_vector_type(8)))  short bf16x8;
typedef __attribute__((ext_vector_type(16))) float f32x16;

__device__ __forceinline__ unsigned short f2bf(float v) {
  unsigned u = __float_as_uint(v);
  return (unsigned short)((u + 0x7FFFu + ((u >> 16) & 1u)) >> 16);
}
// monotone float<->unsigned encoding (for atomicMin on possibly-negative g)
__device__ __forceinline__ unsigned encf(float f) {
  unsigned u = __float_as_uint(f);
  return ((int)u < 0) ? ~u : (u | 0x80000000u);
}
__device__ __forceinline__ float decf(unsigned k) {
  unsigned u = (k & 0x80000000u) ? (k ^ 0x80000000u) : ~k;
  return __uint_as_float(u);
}

// ---------- numpy-pairwise row sums of squares ----------
__device__ __forceinline__ float np_sumsq_128(const float* q, int stride) {
#pragma clang fp contract(off)
  float r[8];
#pragma unroll
  for (int i = 0; i < 8; ++i) { float v = q[i * stride]; r[i] = v * v; }
  for (int blk = 8; blk < 128; blk += 8) {
#pragma unroll
    for (int i = 0; i < 8; ++i) {
      float v = q[(blk + i) * stride];
      float sq = v * v;
      r[i] = r[i] + sq;
    }
  }
  return ((r[0] + r[1]) + (r[2] + r[3])) + ((r[4] + r[5]) + (r[6] + r[7]));
}

// ---------- prep: norms (blocks 0..143) + pack_e 32x32-frag (blocks 144..655)
// pack tile (jg, kf): lane l holds e[j = jg*32 + (l&31)][k = kf*16 + (l>>5)*8 + i]
// flat short offset = ((jg*16 + kf)*64 + l)*8  -> 16 KB contiguous per jg.
__global__ __launch_bounds__(256) void prep_kernel(
    const float* __restrict__ z, const float* __restrict__ emb,
    float* __restrict__ S, float* __restrict__ E, short* __restrict__ ebuf) {
#pragma clang fp contract(off)
  if (blockIdx.x < 144) {
    int t = blockIdx.x * 256 + threadIdx.x;
    if (t < NROWS) {
      int b = t >> 10, hw = t & 1023;
      const float* p = z + (size_t)b * (DIM * HW_) + hw;
      float s0 = np_sumsq_128(p, HW_);
      float s1 = np_sumsq_128(p + 128 * HW_, HW_);
      S[t] = s0 + s1;
    } else if (t < NROWS + KEMB) {
      int j = t - NROWS;
      const float* p = emb + (size_t)j * DIM;
      float s0 = np_sumsq_128(p, 1);
      float s1 = np_sumsq_128(p + 128, 1);
      E[j] = s0 + s1;
    }
  } else {
    int u = (blockIdx.x - 144) * 256 + threadIdx.x;   // 0..131071
    int l = u & 63;
    int kf = (u >> 6) & 15;
    int jg = u >> 10;
    int j = jg * 32 + (l & 31);
    int kb = kf * 16 + (l >> 5) * 8;
    const float* p = emb + (size_t)j * DIM + kb;
    short out[8];
#pragma unroll
    for (int i = 0; i < 8; ++i) out[i] = (short)f2bf(p[i]);
    *(bf16x8*)(ebuf + (size_t)u * 8) = *(bf16x8*)out;
  }
}

// ---------- sweep kernels: 32x32x16 bf16 MFMA, B shared via LDS ----------
// Grid 256 blocks x 512 thr (8 waves). Block = rowgroup rg (512 rows) x
// j-quarter jq (1024 j). Wave w owns rows [rg*512 + w*64, +64) as 2 m-tiles
// of 32. A resident: a[2][16] bf16x8 (128 VGPR). Per 32-j tile: stage 16 KB
// from ebuf2 to LDS (single-buffer m33 pattern), 16 ds_read_b128 + 32 MFMA
// per wave. Layouts: A/B lane = [dim: l&31][k: (l>>5)*8 + i]; C/D:
// col = l&31, row = (reg&3) + 8*(reg>>2) + 4*(l>>5)  [m74/m101 verified].

__device__ __forceinline__ void load_a_frags(
    const float* __restrict__ z, int nbase, int w, int lane, bf16x8 a[2][16]) {
  int b = nbase >> 10, hwb = nbase & 1023;     // 512 | 1024: no b straddle
  const float* zw = z + (size_t)b * (DIM * HW_) + hwb + w * 64 + (lane & 31);
#pragma unroll
  for (int mt = 0; mt < 2; ++mt) {
#pragma unroll
    for (int kf = 0; kf < 16; ++kf) {
      short tmp[8];
#pragma unroll
      for (int i = 0; i < 8; ++i) {
        int k = kf * 16 + (lane >> 5) * 8 + i;
        tmp[i] = (short)f2bf(zw[mt * 32 + (size_t)k * HW_]);
      }
      a[mt][kf] = *(bf16x8*)tmp;
    }
  }
}

__global__ __launch_bounds__(512, 2) void sweep0_kernel(
    const float* __restrict__ z, const short* __restrict__ ebuf,
    const float* __restrict__ E, unsigned* __restrict__ rowmin_enc) {
  __shared__ short btile[8192];                 // 16 KB
  const int t = threadIdx.x, w = t >> 6, lane = t & 63;
  const int rg = blockIdx.x >> 2, jq = blockIdx.x & 3;
  const int nbase = rg * 512;

  bf16x8 a[2][16];
  load_a_frags(z, nbase, w, lane, a);

  const float4* esrc = (const float4*)ebuf;
  const int jg0 = jq * 32;
  float4 pf0 = esrc[(size_t)jg0 * 1024 + t];
  float4 pf1 = esrc[(size_t)jg0 * 1024 + 512 + t];

  float runmin[2][16];
#pragma unroll
  for (int mt = 0; mt < 2; ++mt)
#pragma unroll
    for (int r = 0; r < 16; ++r) runmin[mt][r] = 3.0e38f;

  for (int jt = 0; jt < 32; ++jt) {
    __syncthreads();
    ((float4*)btile)[t] = pf0;
    ((float4*)btile)[512 + t] = pf1;
    __syncthreads();
    if (jt + 1 < 32) {
      pf0 = esrc[(size_t)(jg0 + jt + 1) * 1024 + t];
      pf1 = esrc[(size_t)(jg0 + jt + 1) * 1024 + 512 + t];
    }
    const int jb = jq * 1024 + jt * 32;
    f32x16 acc0 = {0}, acc1 = {0};
    const bf16x8* bt = (const bf16x8*)btile;
#pragma unroll
    for (int kf = 0; kf < 16; ++kf) {
      bf16x8 bf = bt[kf * 64 + lane];
      acc0 = __builtin_amdgcn_mfma_f32_32x32x16_bf16(a[0][kf], bf, acc0, 0, 0, 0);
      acc1 = __builtin_amdgcn_mfma_f32_32x32x16_bf16(a[1][kf], bf, acc1, 0, 0, 0);
    }
    float Ej = E[jb + (lane & 31)];
#pragma unroll
    for (int r = 0; r < 16; ++r) {
      runmin[0][r] = fminf(runmin[0][r], fmaf(-2.0f, acc0[r], Ej));
      runmin[1][r] = fminf(runmin[1][r], fmaf(-2.0f, acc1[r], Ej));
    }
  }
  // min over the 32 j-columns (lanes within each 32-lane half share rows)
#pragma unroll
  for (int mt = 0; mt < 2; ++mt)
#pragma unroll
    for (int r = 0; r < 16; ++r) {
      float m = runmin[mt][r];
#pragma unroll
      for (int mask = 1; mask <= 16; mask <<= 1)
        m = fminf(m, __shfl_xor(m, mask, 64));
      if ((lane & 31) == 0) {
        int row = nbase + w * 64 + mt * 32 + (r & 3) + 8 * (r >> 2) + 4 * (lane >> 5);
        atomicMin(&rowmin_enc[row], encf(m));
      }
    }
}

__global__ __launch_bounds__(512, 2) void sweep1_kernel(
    const float* __restrict__ z, const short* __restrict__ ebuf,
    const float* __restrict__ E, const unsigned* __restrict__ rowmin_enc,
    int* __restrict__ cnt_g, int* __restrict__ cand_g) {
  __shared__ short btile[8192];
  const int t = threadIdx.x, w = t >> 6, lane = t & 63;
  const int rg = blockIdx.x >> 2, jq = blockIdx.x & 3;
  const int nbase = rg * 512;

  bf16x8 a[2][16];
  load_a_frags(z, nbase, w, lane, a);

  float thr[2][16];
#pragma unroll
  for (int mt = 0; mt < 2; ++mt)
#pragma unroll
    for (int r = 0; r < 16; ++r) {
      int row = nbase + w * 64 + mt * 32 + (r & 3) + 8 * (r >> 2) + 4 * (lane >> 5);
      thr[mt][r] = decf(rowmin_enc[row]) + RESCUE_W;
    }

  const float4* esrc = (const float4*)ebuf;
  const int jg0 = jq * 32;
  float4 pf0 = esrc[(size_t)jg0 * 1024 + t];
  float4 pf1 = esrc[(size_t)jg0 * 1024 + 512 + t];

  for (int jt = 0; jt < 32; ++jt) {
    __syncthreads();
    ((float4*)btile)[t] = pf0;
    ((float4*)btile)[512 + t] = pf1;
    __syncthreads();
    if (jt + 1 < 32) {
      pf0 = esrc[(size_t)(jg0 + jt + 1) * 1024 + t];
      pf1 = esrc[(size_t)(jg0 + jt + 1) * 1024 + 512 + t];
    }
    const int jb = jq * 1024 + jt * 32;
    f32x16 acc0 = {0}, acc1 = {0};
    const bf16x8* bt = (const bf16x8*)btile;
#pragma unroll
    for (int kf = 0; kf < 16; ++kf) {
      bf16x8 bf = bt[kf * 64 + lane];
      acc0 = __builtin_amdgcn_mfma_f32_32x32x16_bf16(a[0][kf], bf, acc0, 0, 0, 0);
      acc1 = __builtin_amdgcn_mfma_f32_32x32x16_bf16(a[1][kf], bf, acc1, 0, 0, 0);
    }
    float Ej = E[jb + (lane & 31)];
    int jcol = jb + (lane & 31);
#pragma unroll
    for (int mt = 0; mt < 2; ++mt)
#pragma unroll
      for (int r = 0; r < 16; ++r) {
        float g = fmaf(-2.0f, (mt ? acc1[r] : acc0[r]), Ej);
        if (g <= thr[mt][r]) {
          int row = nbase + w * 64 + mt * 32 + (r & 3) + 8 * (r >> 2) + 4 * (lane >> 5);
          int slot = atomicAdd(&cnt_g[row], 1);
          if (slot < 8) cand_g[(size_t)row * 8 + slot] = jcol;
        }
      }
  }
}

// ---------- rescue: exact np-order chains over per-row candidates ----------
__global__ __launch_bounds__(256) void exact_cand_kernel(
    const float* __restrict__ z, const float* __restrict__ emb,
    const float* __restrict__ S, const float* __restrict__ E,
    const int* __restrict__ cnt_g, const int* __restrict__ cand_g,
    int* __restrict__ idx_out, float* __restrict__ idxf_out) {
  int row = blockIdx.x * 256 + threadIdx.x;
  int b = row >> 10, hw = row & 1023;
  const float* zr = z + (size_t)b * (DIM * HW_) + hw;   // z[k] at zr[k*1024]
  const float s = S[row];
  int c = cnt_g[row];
  float bd = 3.0e38f; int bj = 0x7fffffff;
  if (c <= 8) {
    for (int p = 0; p < c; ++p) {
      int j = cand_g[(size_t)row * 8 + p];
      const float* e = emb + (size_t)j * DIM;
      float acc = 0.0f;
#pragma unroll 8
      for (int k4 = 0; k4 < 64; ++k4) {          // sequential k ascending
        float4 ev = *(const float4*)(e + k4 * 4);
        acc = fmaf(zr[(size_t)(k4 * 4 + 0) * HW_], ev.x, acc);
        acc = fmaf(zr[(size_t)(k4 * 4 + 1) * HW_], ev.y, acc);
        acc = fmaf(zr[(size_t)(k4 * 4 + 2) * HW_], ev.z, acc);
        acc = fmaf(zr[(size_t)(k4 * 4 + 3) * HW_], ev.w, acc);
      }
      float d = fmaf(-2.0f, acc, s + E[j]);
      if (d < bd || (d == bd && j < bj)) { bd = d; bj = j; }
    }
  } else {
    for (int j = 0; j < KEMB; ++j) {             // overflow fallback (P~0)
      const float* e = emb + (size_t)j * DIM;
      float acc = 0.0f;
      for (int k4 = 0; k4 < 64; ++k4) {
        float4 ev = *(const float4*)(e + k4 * 4);
        acc = fmaf(zr[(size_t)(k4 * 4 + 0) * HW_], ev.x, acc);
        acc = fmaf(zr[(size_t)(k4 * 4 + 1) * HW_], ev.y, acc);
        acc = fmaf(zr[(size_t)(k4 * 4 + 2) * HW_], ev.z, acc);
        acc = fmaf(zr[(size_t)(k4 * 4 + 3) * HW_], ev.w, acc);
      }
      float d = fmaf(-2.0f, acc, s + E[j]);
      if (d < bd || (d == bd && j < bj)) { bd = d; bj = j; }
    }
  }
  idx_out[row] = bj;
  idxf_out[row] = (float)bj;
}

// ---------- fallback fp32 kernel (R2 version, known-passing) ----------
#define RT 64
#define JT 256
#define KC 16
__global__ __launch_bounds__(256, 2) void dist_argmin_kernel(
    const float* __restrict__ z, const float* __restrict__ emb,
    const float* __restrict__ S, const float* __restrict__ E,
    int* __restrict__ idx_out, float* __restrict__ idxf_out) {
  __shared__ float zt[DIM * RT];
  __shared__ float et[KC * JT];
  const int t  = threadIdx.x;
  const int g  = t & 31;
  const int tr = t >> 5;
  const int nb = blockIdx.x * RT;
  const int b  = nb >> 10;
  const int hwb = nb & 1023;
  const float* zb = z + (size_t)b * (DIM * HW_) + hwb;
#pragma unroll
  for (int i = 0; i < 16; ++i) {
    int flat = t + i * 256;
    int k  = flat >> 4;
    int r4 = flat & 15;
    float4 v = *(const float4*)(zb + (size_t)k * HW_ + r4 * 4);
    *(float4*)(zt + flat * 4) = v;
  }
  float bestd[8];
  int   bestj[8];
#pragma unroll
  for (int i = 0; i < 8; ++i) { bestd[i] = 3.0e38f; bestj[i] = 0; }
  float Sreg[8];
#pragma unroll
  for (int rr = 0; rr < 8; ++rr) Sreg[rr] = S[nb + tr * 8 + rr];
  float4 pf[4];
#pragma unroll
  for (int q = 0; q < 4; ++q) {
    int cid = q * 256 + t;
    pf[q] = *(const float4*)(emb + (size_t)(cid >> 2) * DIM + (cid & 3) * 4);
  }
  for (int jt = 0; jt < KEMB / JT; ++jt) {
    float acc[8][8];
#pragma unroll
    for (int rr = 0; rr < 8; ++rr)
#pragma unroll
      for (int c = 0; c < 8; ++c) acc[rr][c] = 0.0f;
    for (int kc = 0; kc < DIM / KC; ++kc) {
      __syncthreads();
#pragma unroll
      for (int q = 0; q < 4; ++q) {
        int cid = q * 256 + t;
        int j = cid >> 2, k4 = cid & 3;
        et[(k4 * 4 + 0) * JT + j] = pf[q].x;
        et[(k4 * 4 + 1) * JT + j] = pf[q].y;
        et[(k4 * 4 + 2) * JT + j] = pf[q].z;
        et[(k4 * 4 + 3) * JT + j] = pf[q].w;
      }
      int s = jt * (DIM / KC) + kc + 1;
      if (s < (KEMB / JT) * (DIM / KC)) {
        int njt = s >> 4, nkc = s & 15;
        const float* base = emb + (size_t)njt * JT * DIM + nkc * KC;
#pragma unroll
        for (int q = 0; q < 4; ++q) {
          int cid = q * 256 + t;
          pf[q] = *(const float4*)(base + (size_t)(cid >> 2) * DIM + (cid & 3) * 4);
        }
      }
      __syncthreads();
      const float* ztk = zt + (kc * KC) * RT;
#pragma unroll
      for (int kk = 0; kk < KC; ++kk) {
        float4 z0 = *(const float4*)(ztk + kk * RT + tr * 8);
        float4 z1 = *(const float4*)(ztk + kk * RT + tr * 8 + 4);
        float2 e0 = *(const float2*)(et + kk * JT + g * 2);
        float2 e1 = *(const float2*)(et + kk * JT + 64 + g * 2);
        float2 e2 = *(const float2*)(et + kk * JT + 128 + g * 2);
        float2 e3 = *(const float2*)(et + kk * JT + 192 + g * 2);
        float zr[8] = {z0.x, z0.y, z0.z, z0.w, z1.x, z1.y, z1.z, z1.w};
        float ev[8] = {e0.x, e0.y, e1.x, e1.y, e2.x, e2.y, e3.x, e3.y};
#pragma unroll
        for (int rr = 0; rr < 8; ++rr)
#pragma unroll
          for (int c = 0; c < 8; ++c)
            acc[rr][c] = fmaf(zr[rr], ev[c], acc[rr][c]);
      }
    }
    int jb = jt * JT;
    float Ereg[8];
#pragma unroll
    for (int c = 0; c < 8; ++c)
      Ereg[c] = E[jb + (c >> 1) * 64 + g * 2 + (c & 1)];
#pragma unroll
    for (int rr = 0; rr < 8; ++rr)
#pragma unroll
      for (int c = 0; c < 8; ++c) {
        float A = Sreg[rr] + Ereg[c];
        float d = fmaf(-2.0f, acc[rr][c], A);
        int j = jb + (c >> 1) * 64 + g * 2 + (c & 1);
        if (d < bestd[rr] || (d == bestd[rr] && j < bestj[rr])) {
          bestd[rr] = d; bestj[rr] = j;
        }
      }
  }
  __syncthreads();
  float* rd = et;
  int*   rj = (int*)(et + 2048);
#pragma unroll
  for (int rr = 0; rr < 8; ++rr) {
    rd[(tr * 8 + rr) * 32 + g] = bestd[rr];
    rj[(tr * 8 + rr) * 32 + g] = bestj[rr];
  }
  __syncthreads();
  if (t < RT) {
    float bd = rd[t * 32];
    int   bj = rj[t * 32];
    for (int c = 1; c < 32; ++c) {
      float d2 = rd[t * 32 + c];
      int   j2 = rj[t * 32 + c];
      if (d2 < bd || (d2 == bd && j2 < bj)) { bd = d2; bj = j2; }
    }
    idx_out[nb + t]  = bj;
    idxf_out[nb + t] = (float)bj;
  }
}

// ---------- epilogue: gather + STE + loss, fused finalize (last block) ----------
__global__ __launch_bounds__(256) void epilogue_kernel(
    const float* __restrict__ z, const float* __restrict__ emb,
    const int* __restrict__ idx, float* __restrict__ out0,
    double* __restrict__ loss_sum, int* __restrict__ done,
    float* __restrict__ out_loss) {
#pragma clang fp contract(off)
  __shared__ double wsum[4];
  double acc = 0.0;
#pragma unroll
  for (int it = 0; it < 4; ++it) {
    int u = (it * 2048 + blockIdx.x) * 256 + threadIdx.x;
    int gid = u * 4;
    int hw = gid & 1023;
    int d  = (gid >> 10) & 255;
    int b  = gid >> 18;
    int n  = b * 1024 + hw;
    float4 zp = *(const float4*)(z + gid);
    int4 iv = *(const int4*)(idx + n);
    float q0 = emb[(size_t)iv.x * DIM + d];
    float q1 = emb[(size_t)iv.y * DIM + d];
    float q2 = emb[(size_t)iv.z * DIM + d];
    float q3 = emb[(size_t)iv.w * DIM + d];
    float t0 = q0 - zp.x, t1 = q1 - zp.y, t2 = q2 - zp.z, t3 = q3 - zp.w;
    float4 o; o.x = zp.x + t0; o.y = zp.y + t1; o.z = zp.z + t2; o.w = zp.w + t3;
    *(float4*)(out0 + gid) = o;
    acc += (double)(t0 * t0);
    acc += (double)(t1 * t1);
    acc += (double)(t2 * t2);
    acc += (double)(t3 * t3);
  }
#pragma unroll
  for (int off = 32; off > 0; off >>= 1) acc += __shfl_down(acc, off, 64);
  int lane = threadIdx.x & 63, wv = threadIdx.x >> 6;
  if (lane == 0) wsum[wv] = acc;
  __syncthreads();
  if (threadIdx.x == 0) {
    double bsum = (wsum[0] + wsum[1]) + (wsum[2] + wsum[3]);
    atomicAdd(loss_sum, bsum);
    __threadfence();
    int prev = atomicAdd(done, 1);
    if (prev == 2047) {                       // last block finalizes
      double m = loss_sum[0] / 8388608.0;
      float mf = (float)m;
      float bb = 10.0f * mf;
      out_loss[0] = mf + bb;
    }
  }
}

extern "C" void kernel_launch(void* const* d_in, const int* in_sizes, int n_in,
                              void* d_out, int out_size, void* d_ws, size_t ws_size,
                              hipStream_t stream) {
  const float* z   = (const float*)d_in[0];
  const float* emb = (const float*)d_in[1];
  float* out = (float*)d_out;
  char* ws = (char*)d_ws;
  int*    idx = (int*)ws;
  float*  S   = (float*)(ws + WS_S_OFF);
  float*  E   = (float*)(ws + WS_E_OFF);
  double* ls  = (double*)(ws + WS_LOSS_OFF);
  int*    done = (int*)(ws + WS_DONE_OFF);

  // zero loss+done+cnt; fill rowmin with +inf keys (0xFF)
  hipMemsetAsync(ws + WS_LOSS_OFF, 0, WS_RMIN_OFF - WS_LOSS_OFF, stream);
  hipMemsetAsync(ws + WS_RMIN_OFF, 0xFF, WS_CAND_OFF - WS_RMIN_OFF, stream);

  if (ws_size >= (size_t)WS_NEEDED) {
    int*      cnt    = (int*)(ws + WS_CNT_OFF);
    unsigned* rowmin = (unsigned*)(ws + WS_RMIN_OFF);
    int*      cand   = (int*)(ws + WS_CAND_OFF);
    short*    ebuf   = (short*)(ws + WS_EBUF_OFF);
    prep_kernel<<<656, 256, 0, stream>>>(z, emb, S, E, ebuf);
    sweep0_kernel<<<256, 512, 0, stream>>>(z, ebuf, E, rowmin);
    sweep1_kernel<<<256, 512, 0, stream>>>(z, ebuf, E, rowmin, cnt, cand);
    exact_cand_kernel<<<128, 256, 0, stream>>>(z, emb, S, E, cnt, cand, idx,
                                               out + 8388609);
  } else {
    prep_kernel<<<656, 256, 0, stream>>>(z, emb, S, E, (short*)(ws + WS_CAND_OFF));
    dist_argmin_kernel<<<NROWS / RT, 256, 0, stream>>>(z, emb, S, E, idx,
                                                       out + 8388609);
  }

  epilogue_kernel<<<2048, 256, 0, stream>>>(z, emb, idx, out, ls, done,
                                            out + 8388608);
}